// Round 6
// baseline (159.544 us; speedup 1.0000x reference)
//
#include <hip/hip_runtime.h>
#include <cstdint>
#include <cstddef>

#define S 8192
#define Dm 1024
#define E 64
#define CAP 128
#define SEC 67108864ull   // S*E*CAP
// out layout (float32 elements):
//   [0] l_aux | [1,1+SEC) combine | [1+SEC,1+2SEC) dispatch | [1+2SEC,+64) counts
// out_size = 1 + 2*SEC + 64 = 134,217,793. Fill covers the first 134,217,792;
// the leftover element is exp_counts[63], written unconditionally by k_scan.

#define GEMM_BLOCKS 128   // 64 tokens x 64 experts each
#define FILL_BLOCKS 2048

typedef float f32x4 __attribute__((ext_vector_type(4)));

// ---------------- K1: fused {GEMM+softmax+argmax} + 537MB zero-fill ----------
// GEMM blocks [0,128): thread = (token tid&63, expert-16-group tid>>6).
//   Per 64-K chunk, BOTH A (64x64) and W (64x64) staged in LDS; inner loop is
//   LDS-only (R5 win). W re-fetch halved vs R5: 128 blocks x 256 KB = 32 MB.
//   W LDS reads are full-wave broadcast (eo wave-uniform). Next chunk's 8
//   global float4 loads issued right after the LDS-ready barrier (T14).
// Fill blocks [128,2176): grid-stride NON-TEMPORAL float4 zero of the output:
//   nt stores don't thrash L2, so W/x lines stay cached for the GEMM (R5's
//   remaining stall source). Fill is HBM-write-bound ~81us; GEMM hides under.
__global__ __launch_bounds__(256) void k_main(const float* __restrict__ x,
                                              const float* __restrict__ w,
                                              float* __restrict__ gate,
                                              int* __restrict__ idx,
                                              float* __restrict__ me_part,
                                              float* __restrict__ out) {
    int bid = blockIdx.x;
    int tid = threadIdx.x;
    if (bid < GEMM_BLOCKS) {
        __shared__ float Al[64][66];   // 264B rows, 8B-aligned, 2-way max
        __shared__ float Wl[64][68];   // 272B rows, 16B-aligned
        __shared__ float sm[64];
        __shared__ float sinv[64];
        int tok = tid & 63;            // local token (= lane)
        int eo = tid >> 6;             // expert-16-group 0..3 (wave-uniform)
        int t0 = bid * 64;
        int r = tid >> 3;              // staging row 0..31
        int c = (tid & 7) * 8;         // staging col
        const float* asrc0 = x + (size_t)(t0 + r) * Dm + c;
        const float* asrc1 = asrc0 + 32 * (size_t)Dm;
        const float* wsrc0 = w + (size_t)r * Dm + c;
        const float* wsrc1 = wsrc0 + 32 * (size_t)Dm;
        float* adst0 = &Al[r][c];
        float* adst1 = &Al[32 + r][c];
        float* wdst0 = &Wl[r][c];
        float* wdst1 = &Wl[32 + r][c];

        float acc[16];
#pragma unroll
        for (int i = 0; i < 16; ++i) acc[i] = 0.f;
        // prefetch registers (8 float4)
        float4 pa0 = *(const float4*)(asrc0 + 0);
        float4 pa1 = *(const float4*)(asrc0 + 4);
        float4 pa2 = *(const float4*)(asrc1 + 0);
        float4 pa3 = *(const float4*)(asrc1 + 4);
        float4 pw0 = *(const float4*)(wsrc0 + 0);
        float4 pw1 = *(const float4*)(wsrc0 + 4);
        float4 pw2 = *(const float4*)(wsrc1 + 0);
        float4 pw3 = *(const float4*)(wsrc1 + 4);

        for (int ch = 0; ch < 16; ++ch) {
            __syncthreads();           // previous compute done; LDS writable
            *(float2*)(adst0 + 0) = make_float2(pa0.x, pa0.y);
            *(float2*)(adst0 + 2) = make_float2(pa0.z, pa0.w);
            *(float2*)(adst0 + 4) = make_float2(pa1.x, pa1.y);
            *(float2*)(adst0 + 6) = make_float2(pa1.z, pa1.w);
            *(float2*)(adst1 + 0) = make_float2(pa2.x, pa2.y);
            *(float2*)(adst1 + 2) = make_float2(pa2.z, pa2.w);
            *(float2*)(adst1 + 4) = make_float2(pa3.x, pa3.y);
            *(float2*)(adst1 + 6) = make_float2(pa3.z, pa3.w);
            *(float4*)(wdst0 + 0) = pw0;
            *(float4*)(wdst0 + 4) = pw1;
            *(float4*)(wdst1 + 0) = pw2;
            *(float4*)(wdst1 + 4) = pw3;
            __syncthreads();           // LDS ready
            if (ch < 15) {             // issue next chunk's loads (hidden)
                int kb = (ch + 1) * 64;
                pa0 = *(const float4*)(asrc0 + kb);
                pa1 = *(const float4*)(asrc0 + kb + 4);
                pa2 = *(const float4*)(asrc1 + kb);
                pa3 = *(const float4*)(asrc1 + kb + 4);
                pw0 = *(const float4*)(wsrc0 + kb);
                pw1 = *(const float4*)(wsrc0 + kb + 4);
                pw2 = *(const float4*)(wsrc1 + kb);
                pw3 = *(const float4*)(wsrc1 + kb + 4);
            }
            // LDS-only inner loop: per k4 = 2 b64 (A, 2-way) + 16 b128
            // (W, wave-broadcast) + 64 FMA
#pragma unroll 2
            for (int k4 = 0; k4 < 16; ++k4) {
                float2 aa = *(const float2*)&Al[tok][k4 * 4];
                float2 ab = *(const float2*)&Al[tok][k4 * 4 + 2];
#pragma unroll
                for (int j = 0; j < 16; ++j) {
                    float4 wv = *(const float4*)&Wl[eo * 16 + j][k4 * 4];
                    acc[j] = fmaf(ab.y, wv.w, fmaf(ab.x, wv.z,
                             fmaf(aa.y, wv.y, fmaf(aa.x, wv.x, acc[j]))));
                }
            }
        }
        __syncthreads();
        // ---- epilogue: logits tile -> LDS (reuse Al), softmax/argmax ----
#pragma unroll
        for (int j = 0; j < 16; ++j) Al[tok][eo * 16 + j] = acc[j];
        __syncthreads();
        if (tid < 64) {   // row phase: first-index argmax + exp-sum
            float m = Al[tid][0];
            int am = 0;
#pragma unroll
            for (int cc = 1; cc < E; ++cc) {
                float v = Al[tid][cc];
                if (v > m) { m = v; am = cc; }
            }
            float ssum = 0.f;
#pragma unroll
            for (int cc = 0; cc < E; ++cc) ssum += __expf(Al[tid][cc] - m);
            float inv = 1.0f / ssum;   // softmax value at the argmax
            gate[t0 + tid] = inv;
            idx[t0 + tid] = am;
            sm[tid] = m;
            sinv[tid] = inv;
        }
        __syncthreads();
        if (tid < E) {    // column phase: partial me sums (deterministic)
            float cs = 0.f;
#pragma unroll 8
            for (int rr = 0; rr < 64; ++rr)
                cs += __expf(Al[rr][tid] - sm[rr]) * sinv[rr];
            me_part[bid * E + tid] = cs;
        }
    } else {
        int fb = bid - GEMM_BLOCKS;
        const unsigned N4 = (unsigned)((1ull + 2ull * SEC + 64ull) / 4ull);  // 33,554,448
        f32x4 z = {0.f, 0.f, 0.f, 0.f};
        f32x4* o4 = (f32x4*)out;
        for (unsigned i = (unsigned)fb * 256u + tid; i < N4; i += FILL_BLOCKS * 256u)
            __builtin_nontemporal_store(z, o4 + i);   // nt: don't thrash L2
    }
}

// ---------------- K2: ordered scan + scatter + counts + me-reduce + l_aux ----
// 64 blocks (one per expert) x 256 threads; deterministic ballot scan in
// token order; scatters combine/dispatch inline (out already zeroed by K1).
__global__ __launch_bounds__(256) void k_scan(const int* __restrict__ idx,
                                              const float* __restrict__ gate,
                                              const float* __restrict__ me_part,
                                              float* __restrict__ out) {
    int e = blockIdx.x;
    int tid = threadIdx.x;
    int lane = tid & 63;
    int wid = tid >> 6;
    __shared__ int wsum[4];
    __shared__ float red[256];
    int running = 0;
    for (int ch = 0; ch < S / 256; ++ch) {
        int t = ch * 256 + tid;
        bool f = (idx[t] == e);
        unsigned long long b = __ballot(f);
        int pre = __popcll(b & ((1ull << lane) - 1ull));
        if (lane == 0) wsum[wid] = __popcll(b);
        __syncthreads();
        int off = running;
#pragma unroll
        for (int w2 = 0; w2 < 4; ++w2)
            if (w2 < wid) off += wsum[w2];
        int p = off + pre;
        if (f && p < CAP) {
            size_t o = 1 + (size_t)t * (E * CAP) + (size_t)e * CAP + (size_t)p;
            out[o] = gate[t];                 // combine_weights
            out[o + (size_t)SEC] = 1.0f;      // dispatch_mask
        }
        running += wsum[0] + wsum[1] + wsum[2] + wsum[3];
        __syncthreads();
    }
    // me reduction: me_sum[e] = sum over 128 GEMM blocks' partials
    red[tid] = (tid < GEMM_BLOCKS) ? me_part[tid * E + e] : 0.f;
    __syncthreads();
    for (int s2 = 128; s2 > 0; s2 >>= 1) {
        if (tid < s2) red[tid] += red[tid + s2];
        __syncthreads();
    }
    if (tid == 0) {
        out[1 + 2 * (size_t)SEC + e] = (float)running;   // exp_counts (pre-drop)
        float la = red[0] * (1.0f / (float)S) *
                   ((float)running / (float)S) * (float)E;
        atomicAdd(out, la);                              // l_aux
    }
}

extern "C" void kernel_launch(void* const* d_in, const int* in_sizes, int n_in,
                              void* d_out, int out_size, void* d_ws, size_t ws_size,
                              hipStream_t stream) {
    const float* x = (const float*)d_in[0];      // [S, Dm] fp32
    const float* w = (const float*)d_in[1];      // [E, Dm] fp32
    float* out = (float*)d_out;

    // ws layout
    float* me_part = (float*)d_ws;               // [128][64] floats = 32 KB
    float* gate = me_part + GEMM_BLOCKS * E;     // S floats
    int* idx = (int*)(gate + S);                 // S ints

    k_main<<<dim3(GEMM_BLOCKS + FILL_BLOCKS), dim3(256), 0, stream>>>(
        x, w, gate, idx, me_part, out);
    k_scan<<<dim3(64), dim3(256), 0, stream>>>(idx, gate, me_part, out);
}

// Round 7
// 145.723 us; speedup vs baseline: 1.0948x; 1.0948x over previous
//
#include <hip/hip_runtime.h>
#include <cstdint>
#include <cstddef>

#define S 8192
#define Dm 1024
#define E 64
#define CAP 128
#define SEC 67108864ull   // S*E*CAP
// out layout (float32 elements):
//   [0] l_aux | [1,1+SEC) combine | [1+SEC,1+2SEC) dispatch | [1+2SEC,+64) counts
// out_size = 1 + 2*SEC + 64 = 134,217,793. Fill covers the first 134,217,792;
// the leftover element is exp_counts[63], written unconditionally by k_scan.

#define GEMM_BLOCKS 256   // 32 tokens x 64 experts each (exact R5 structure)
#define FILL_BLOCKS 2048

typedef float f32x4 __attribute__((ext_vector_type(4)));

// ---------------- K1: fused {GEMM+softmax+argmax} + 537MB zero-fill ----------
// EXACT R5 structure (140.8us baseline); single change this round: the fill
// uses NON-TEMPORAL stores. A/B isolates R6's regression culprit (rule #13).
// Theory: nt keeps the 537MB write stream from evicting W/x in L2, so the
// GEMM's prefetch loads become L2 hits -> k_main shrinks toward the fill
// floor. If instead nt writes are intrinsically slower, we reproduce R6's
// +19us and nt is convicted.
__global__ __launch_bounds__(256) void k_main(const float* __restrict__ x,
                                              const float* __restrict__ w,
                                              float* __restrict__ gate,
                                              int* __restrict__ idx,
                                              float* __restrict__ me_part,
                                              float* __restrict__ out) {
    int bid = blockIdx.x;
    int tid = threadIdx.x;
    if (bid < GEMM_BLOCKS) {
        __shared__ float Al[32][66];   // row 264B: float2-aligned, 2-way max
        __shared__ float Wl[64][68];   // row 272B: float4-aligned, 2-way max
        __shared__ float sm[32];
        __shared__ float sinv[32];
        int tok = tid & 31;            // local token
        int eo = tid >> 5;             // expert octet 0..7
        int t0 = bid * 32;
        // staging maps: thread -> row tid>>3, 8 floats at col (tid&7)*8
        const float* asrc = x + (size_t)(t0 + (tid >> 3)) * Dm + (tid & 7) * 8;
        const float* wsrc0 = w + (size_t)(tid >> 3) * Dm + (tid & 7) * 8;
        const float* wsrc1 = wsrc0 + 32 * (size_t)Dm;
        float* adst = &Al[tid >> 3][(tid & 7) * 8];
        float* wdst0 = &Wl[tid >> 3][(tid & 7) * 8];
        float* wdst1 = &Wl[32 + (tid >> 3)][(tid & 7) * 8];

        float acc[8] = {0.f, 0.f, 0.f, 0.f, 0.f, 0.f, 0.f, 0.f};
        // prefetch registers (6 float4)
        float4 pa0 = *(const float4*)(asrc + 0);
        float4 pa1 = *(const float4*)(asrc + 4);
        float4 pw0 = *(const float4*)(wsrc0 + 0);
        float4 pw1 = *(const float4*)(wsrc0 + 4);
        float4 pw2 = *(const float4*)(wsrc1 + 0);
        float4 pw3 = *(const float4*)(wsrc1 + 4);

        for (int ch = 0; ch < 16; ++ch) {
            __syncthreads();           // previous compute done; LDS writable
            // regs -> LDS (A as float2: 264B rows are only 8B-aligned)
            *(float2*)(adst + 0) = make_float2(pa0.x, pa0.y);
            *(float2*)(adst + 2) = make_float2(pa0.z, pa0.w);
            *(float2*)(adst + 4) = make_float2(pa1.x, pa1.y);
            *(float2*)(adst + 6) = make_float2(pa1.z, pa1.w);
            *(float4*)(wdst0 + 0) = pw0;
            *(float4*)(wdst0 + 4) = pw1;
            *(float4*)(wdst1 + 0) = pw2;
            *(float4*)(wdst1 + 4) = pw3;
            __syncthreads();           // LDS ready
            if (ch < 15) {             // issue next chunk's loads (latency hidden)
                int kb = (ch + 1) * 64;
                pa0 = *(const float4*)(asrc + kb);
                pa1 = *(const float4*)(asrc + kb + 4);
                pw0 = *(const float4*)(wsrc0 + kb);
                pw1 = *(const float4*)(wsrc0 + kb + 4);
                pw2 = *(const float4*)(wsrc1 + kb);
                pw3 = *(const float4*)(wsrc1 + kb + 4);
            }
            // LDS-only inner loop: per k4 = 2 b64 (A) + 8 b128 (W, half-wave
            // broadcast) + 32 FMA
#pragma unroll 4
            for (int k4 = 0; k4 < 16; ++k4) {
                float2 aa = *(const float2*)&Al[tok][k4 * 4];
                float2 ab = *(const float2*)&Al[tok][k4 * 4 + 2];
#pragma unroll
                for (int j = 0; j < 8; ++j) {
                    float4 wv = *(const float4*)&Wl[eo * 8 + j][k4 * 4];
                    acc[j] = fmaf(ab.y, wv.w, fmaf(ab.x, wv.z,
                             fmaf(aa.y, wv.y, fmaf(aa.x, wv.x, acc[j]))));
                }
            }
        }
        __syncthreads();
        // ---- epilogue: logits tile -> LDS (reuse Al), softmax/argmax ----
#pragma unroll
        for (int j = 0; j < 8; ++j) Al[tok][eo * 8 + j] = acc[j];
        __syncthreads();
        if (tid < 32) {   // row phase: first-index argmax + exp-sum
            float m = Al[tid][0];
            int am = 0;
#pragma unroll
            for (int c = 1; c < E; ++c) {
                float v = Al[tid][c];
                if (v > m) { m = v; am = c; }
            }
            float ssum = 0.f;
#pragma unroll
            for (int c = 0; c < E; ++c) ssum += __expf(Al[tid][c] - m);
            float inv = 1.0f / ssum;   // softmax value at the argmax
            gate[t0 + tid] = inv;
            idx[t0 + tid] = am;
            sm[tid] = m;
            sinv[tid] = inv;
        }
        __syncthreads();
        if (tid < E) {    // column phase: partial me sums (deterministic)
            float cs = 0.f;
#pragma unroll 8
            for (int r = 0; r < 32; ++r)
                cs += __expf(Al[r][tid] - sm[r]) * sinv[r];
            me_part[bid * E + tid] = cs;
        }
    } else {
        int fb = bid - GEMM_BLOCKS;
        const unsigned N4 = (unsigned)((1ull + 2ull * SEC + 64ull) / 4ull);  // 33,554,448
        f32x4 z = {0.f, 0.f, 0.f, 0.f};
        f32x4* o4 = (f32x4*)out;
        for (unsigned i = (unsigned)fb * 256u + tid; i < N4; i += FILL_BLOCKS * 256u)
            __builtin_nontemporal_store(z, o4 + i);   // THE single change vs R5
    }
}

// ---------------- K2: ordered scan + scatter + counts + me-reduce + l_aux ----
// 64 blocks (one per expert) x 256 threads; deterministic ballot scan in
// token order; scatters combine/dispatch inline (out already zeroed by K1).
__global__ __launch_bounds__(256) void k_scan(const int* __restrict__ idx,
                                              const float* __restrict__ gate,
                                              const float* __restrict__ me_part,
                                              float* __restrict__ out) {
    int e = blockIdx.x;
    int tid = threadIdx.x;
    int lane = tid & 63;
    int wid = tid >> 6;
    __shared__ int wsum[4];
    __shared__ float red[256];
    int running = 0;
    for (int ch = 0; ch < S / 256; ++ch) {
        int t = ch * 256 + tid;
        bool f = (idx[t] == e);
        unsigned long long b = __ballot(f);
        int pre = __popcll(b & ((1ull << lane) - 1ull));
        if (lane == 0) wsum[wid] = __popcll(b);
        __syncthreads();
        int off = running;
#pragma unroll
        for (int w2 = 0; w2 < 4; ++w2)
            if (w2 < wid) off += wsum[w2];
        int p = off + pre;
        if (f && p < CAP) {
            size_t o = 1 + (size_t)t * (E * CAP) + (size_t)e * CAP + (size_t)p;
            out[o] = gate[t];                 // combine_weights
            out[o + (size_t)SEC] = 1.0f;      // dispatch_mask
        }
        running += wsum[0] + wsum[1] + wsum[2] + wsum[3];
        __syncthreads();
    }
    // me reduction: me_sum[e] = sum over 256 blocks' partials
    red[tid] = me_part[tid * E + e];
    __syncthreads();
    for (int s2 = 128; s2 > 0; s2 >>= 1) {
        if (tid < s2) red[tid] += red[tid + s2];
        __syncthreads();
    }
    if (tid == 0) {
        out[1 + 2 * (size_t)SEC + e] = (float)running;   // exp_counts (pre-drop)
        float la = red[0] * (1.0f / (float)S) *
                   ((float)running / (float)S) * (float)E;
        atomicAdd(out, la);                              // l_aux
    }
}

extern "C" void kernel_launch(void* const* d_in, const int* in_sizes, int n_in,
                              void* d_out, int out_size, void* d_ws, size_t ws_size,
                              hipStream_t stream) {
    const float* x = (const float*)d_in[0];      // [S, Dm] fp32
    const float* w = (const float*)d_in[1];      // [E, Dm] fp32
    float* out = (float*)d_out;

    // ws layout
    float* me_part = (float*)d_ws;               // [256][64] floats = 64 KB
    float* gate = me_part + GEMM_BLOCKS * E;     // S floats
    int* idx = (int*)(gate + S);                 // S ints

    k_main<<<dim3(GEMM_BLOCKS + FILL_BLOCKS), dim3(256), 0, stream>>>(
        x, w, gate, idx, me_part, out);
    k_scan<<<dim3(64), dim3(256), 0, stream>>>(idx, gate, me_part, out);
}

// Round 8
// 140.459 us; speedup vs baseline: 1.1359x; 1.0375x over previous
//
#include <hip/hip_runtime.h>
#include <cstdint>
#include <cstddef>

#define S 8192
#define Dm 1024
#define E 64
#define CAP 128
#define SEC 67108864ull   // S*E*CAP
// out layout (float32 elements):
//   [0] l_aux | [1,1+SEC) combine | [1+SEC,1+2SEC) dispatch | [1+2SEC,+64) counts
// out_size = 1 + 2*SEC + 64 = 134,217,793. Fill covers the first 134,217,792;
// the leftover element is exp_counts[63], written unconditionally by k_scan.

#define GEMM_BLOCKS 256   // 32 tokens x 64 experts each (R5 structure)
#define FILL_BLOCKS 1792  // 256+1792 = 2048 = 256 CU x 8 blocks: all co-resident

typedef float f32x4 __attribute__((ext_vector_type(4)));

// ---------------- K1: fused {GEMM+softmax+argmax} + 537MB zero-fill ----------
// R5 structure (140.8us champion). Two changes, same mechanism (scheduling):
//   1. normal stores for the fill (nt convicted by R7 A/B: +5us)
//   2. grid sized to EXACTLY the chip's 2048 block slots -> no 256-block
//      overflow tail (R5/R7 had 2304 blocks > 2048 slots: a 64MB write quota
//      started only after slots freed, serializing a ~10us tail).
__global__ __launch_bounds__(256) void k_main(const float* __restrict__ x,
                                              const float* __restrict__ w,
                                              float* __restrict__ gate,
                                              int* __restrict__ idx,
                                              float* __restrict__ me_part,
                                              float* __restrict__ out) {
    int bid = blockIdx.x;
    int tid = threadIdx.x;
    if (bid < GEMM_BLOCKS) {
        __shared__ float Al[32][66];   // row 264B: float2-aligned, 2-way max
        __shared__ float Wl[64][68];   // row 272B: float4-aligned, 2-way max
        __shared__ float sm[32];
        __shared__ float sinv[32];
        int tok = tid & 31;            // local token
        int eo = tid >> 5;             // expert octet 0..7
        int t0 = bid * 32;
        // staging maps: thread -> row tid>>3, 8 floats at col (tid&7)*8
        const float* asrc = x + (size_t)(t0 + (tid >> 3)) * Dm + (tid & 7) * 8;
        const float* wsrc0 = w + (size_t)(tid >> 3) * Dm + (tid & 7) * 8;
        const float* wsrc1 = wsrc0 + 32 * (size_t)Dm;
        float* adst = &Al[tid >> 3][(tid & 7) * 8];
        float* wdst0 = &Wl[tid >> 3][(tid & 7) * 8];
        float* wdst1 = &Wl[32 + (tid >> 3)][(tid & 7) * 8];

        float acc[8] = {0.f, 0.f, 0.f, 0.f, 0.f, 0.f, 0.f, 0.f};
        // prefetch registers (6 float4)
        float4 pa0 = *(const float4*)(asrc + 0);
        float4 pa1 = *(const float4*)(asrc + 4);
        float4 pw0 = *(const float4*)(wsrc0 + 0);
        float4 pw1 = *(const float4*)(wsrc0 + 4);
        float4 pw2 = *(const float4*)(wsrc1 + 0);
        float4 pw3 = *(const float4*)(wsrc1 + 4);

        for (int ch = 0; ch < 16; ++ch) {
            __syncthreads();           // previous compute done; LDS writable
            // regs -> LDS (A as float2: 264B rows are only 8B-aligned)
            *(float2*)(adst + 0) = make_float2(pa0.x, pa0.y);
            *(float2*)(adst + 2) = make_float2(pa0.z, pa0.w);
            *(float2*)(adst + 4) = make_float2(pa1.x, pa1.y);
            *(float2*)(adst + 6) = make_float2(pa1.z, pa1.w);
            *(float4*)(wdst0 + 0) = pw0;
            *(float4*)(wdst0 + 4) = pw1;
            *(float4*)(wdst1 + 0) = pw2;
            *(float4*)(wdst1 + 4) = pw3;
            __syncthreads();           // LDS ready
            if (ch < 15) {             // issue next chunk's loads (latency hidden)
                int kb = (ch + 1) * 64;
                pa0 = *(const float4*)(asrc + kb);
                pa1 = *(const float4*)(asrc + kb + 4);
                pw0 = *(const float4*)(wsrc0 + kb);
                pw1 = *(const float4*)(wsrc0 + kb + 4);
                pw2 = *(const float4*)(wsrc1 + kb);
                pw3 = *(const float4*)(wsrc1 + kb + 4);
            }
            // LDS-only inner loop: per k4 = 2 b64 (A) + 8 b128 (W, half-wave
            // broadcast) + 32 FMA
#pragma unroll 4
            for (int k4 = 0; k4 < 16; ++k4) {
                float2 aa = *(const float2*)&Al[tok][k4 * 4];
                float2 ab = *(const float2*)&Al[tok][k4 * 4 + 2];
#pragma unroll
                for (int j = 0; j < 8; ++j) {
                    float4 wv = *(const float4*)&Wl[eo * 8 + j][k4 * 4];
                    acc[j] = fmaf(ab.y, wv.w, fmaf(ab.x, wv.z,
                             fmaf(aa.y, wv.y, fmaf(aa.x, wv.x, acc[j]))));
                }
            }
        }
        __syncthreads();
        // ---- epilogue: logits tile -> LDS (reuse Al), softmax/argmax ----
#pragma unroll
        for (int j = 0; j < 8; ++j) Al[tok][eo * 8 + j] = acc[j];
        __syncthreads();
        if (tid < 32) {   // row phase: first-index argmax + exp-sum
            float m = Al[tid][0];
            int am = 0;
#pragma unroll
            for (int c = 1; c < E; ++c) {
                float v = Al[tid][c];
                if (v > m) { m = v; am = c; }
            }
            float ssum = 0.f;
#pragma unroll
            for (int c = 0; c < E; ++c) ssum += __expf(Al[tid][c] - m);
            float inv = 1.0f / ssum;   // softmax value at the argmax
            gate[t0 + tid] = inv;
            idx[t0 + tid] = am;
            sm[tid] = m;
            sinv[tid] = inv;
        }
        __syncthreads();
        if (tid < E) {    // column phase: partial me sums (deterministic)
            float cs = 0.f;
#pragma unroll 8
            for (int r = 0; r < 32; ++r)
                cs += __expf(Al[r][tid] - sm[r]) * sinv[r];
            me_part[bid * E + tid] = cs;
        }
    } else {
        int fb = bid - GEMM_BLOCKS;
        const unsigned N4 = (unsigned)((1ull + 2ull * SEC + 64ull) / 4ull);  // 33,554,448
        f32x4 z = {0.f, 0.f, 0.f, 0.f};
        f32x4* o4 = (f32x4*)out;
        for (unsigned i = (unsigned)fb * 256u + tid; i < N4; i += FILL_BLOCKS * 256u)
            o4[i] = z;   // normal store (nt reverted per R7 A/B)
    }
}

// ---------------- K2: ordered scan + scatter + counts + me-reduce + l_aux ----
// 64 blocks (one per expert) x 256 threads; deterministic ballot scan in
// token order; scatters combine/dispatch inline (out already zeroed by K1).
__global__ __launch_bounds__(256) void k_scan(const int* __restrict__ idx,
                                              const float* __restrict__ gate,
                                              const float* __restrict__ me_part,
                                              float* __restrict__ out) {
    int e = blockIdx.x;
    int tid = threadIdx.x;
    int lane = tid & 63;
    int wid = tid >> 6;
    __shared__ int wsum[4];
    __shared__ float red[256];
    int running = 0;
    for (int ch = 0; ch < S / 256; ++ch) {
        int t = ch * 256 + tid;
        bool f = (idx[t] == e);
        unsigned long long b = __ballot(f);
        int pre = __popcll(b & ((1ull << lane) - 1ull));
        if (lane == 0) wsum[wid] = __popcll(b);
        __syncthreads();
        int off = running;
#pragma unroll
        for (int w2 = 0; w2 < 4; ++w2)
            if (w2 < wid) off += wsum[w2];
        int p = off + pre;
        if (f && p < CAP) {
            size_t o = 1 + (size_t)t * (E * CAP) + (size_t)e * CAP + (size_t)p;
            out[o] = gate[t];                 // combine_weights
            out[o + (size_t)SEC] = 1.0f;      // dispatch_mask
        }
        running += wsum[0] + wsum[1] + wsum[2] + wsum[3];
        __syncthreads();
    }
    // me reduction: me_sum[e] = sum over 256 blocks' partials
    red[tid] = me_part[tid * E + e];
    __syncthreads();
    for (int s2 = 128; s2 > 0; s2 >>= 1) {
        if (tid < s2) red[tid] += red[tid + s2];
        __syncthreads();
    }
    if (tid == 0) {
        out[1 + 2 * (size_t)SEC + e] = (float)running;   // exp_counts (pre-drop)
        float la = red[0] * (1.0f / (float)S) *
                   ((float)running / (float)S) * (float)E;
        atomicAdd(out, la);                              // l_aux
    }
}

extern "C" void kernel_launch(void* const* d_in, const int* in_sizes, int n_in,
                              void* d_out, int out_size, void* d_ws, size_t ws_size,
                              hipStream_t stream) {
    const float* x = (const float*)d_in[0];      // [S, Dm] fp32
    const float* w = (const float*)d_in[1];      // [E, Dm] fp32
    float* out = (float*)d_out;

    // ws layout
    float* me_part = (float*)d_ws;               // [256][64] floats = 64 KB
    float* gate = me_part + GEMM_BLOCKS * E;     // S floats
    int* idx = (int*)(gate + S);                 // S ints

    k_main<<<dim3(GEMM_BLOCKS + FILL_BLOCKS), dim3(256), 0, stream>>>(
        x, w, gate, idx, me_part, out);
    k_scan<<<dim3(64), dim3(256), 0, stream>>>(idx, gate, me_part, out);
}